// Round 6
// baseline (261.145 us; speedup 1.0000x reference)
//
#include <hip/hip_runtime.h>

#define TEX_W 2048
#define TEX_H 2048
#define N_TEXELS (TEX_W * TEX_H)
#define RGBA_BYTES ((size_t)N_TEXELS * 16)

// ===========================================================================
// Pass A: stream-repack RGB (12 B/texel) -> RGBA (16 B/texel) in d_ws.
// Each thread: 4 texels = three aligned float4 reads, four aligned
// float4 writes. Fully coalesced.
// ===========================================================================
__global__ __launch_bounds__(256) void dtx_repack(
    const float4* __restrict__ src,   // texture viewed as float4[3*N/4]
    float4* __restrict__ dst,         // RGBA texels [N]
    int quads)                        // N_TEXELS / 4
{
    int t = blockIdx.x * blockDim.x + threadIdx.x;
    if (t >= quads) return;
    float4 s0 = src[3 * t + 0];
    float4 s1 = src[3 * t + 1];
    float4 s2 = src[3 * t + 2];
    dst[4 * t + 0] = make_float4(s0.x, s0.y, s0.z, 0.0f);
    dst[4 * t + 1] = make_float4(s0.w, s1.x, s1.y, 0.0f);
    dst[4 * t + 2] = make_float4(s1.z, s1.w, s2.x, 0.0f);
    dst[4 * t + 3] = make_float4(s2.y, s2.z, s2.w, 0.0f);
}

// ===========================================================================
// Pass B: bilinear gather. EXACTLY the R1-passing index math (u1=ceil(u),
// v1=ceil(v), no selects) — only the texel fetch changes: one aligned
// float4 load per corner from the RGBA buffer. All indices in-bounds:
// u1,v1 <= 2047.
// ===========================================================================
__global__ __launch_bounds__(256) void dtx_gather(
    const float* __restrict__ uvs,
    const float4* __restrict__ texq,  // RGBA texels, [x][y]
    float* __restrict__ out,
    int n)
{
    int i = blockIdx.x * blockDim.x + threadIdx.x;
    if (i >= n) return;

    float2 uv = reinterpret_cast<const float2*>(uvs)[i];

    // map [-1,1] -> [0, dim-1] texel coords, exactly as reference
    float u = (uv.x + 1.0f) * 0.5f * (float)(TEX_W - 1);
    float v = (uv.y + 1.0f) * 0.5f * (float)(TEX_H - 1);

    float fu0 = floorf(u);
    float fv0 = floorf(v);
    int u0 = (int)fu0;
    int v0 = (int)fv0;
    int u1 = (int)ceilf(u);
    int v1 = (int)ceilf(v);

    float a = u - fu0;
    float b = v - fv0;
    float ia = 1.0f - a;
    float ib = 1.0f - b;

    int r0 = u0 * TEX_H;
    int r1 = u1 * TEX_H;

    float4 t00 = texq[r0 + v0];
    float4 t10 = texq[r1 + v0];
    float4 t01 = texq[r0 + v1];
    float4 t11 = texq[r1 + v1];

    // exact reference association:
    // (t00*a + t10*(1-a))*b + (t01*a + t11*(1-a))*(1-b)
    float ox = (t00.x * a + t10.x * ia) * b + (t01.x * a + t11.x * ia) * ib;
    float oy = (t00.y * a + t10.y * ia) * b + (t01.y * a + t11.y * ia) * ib;
    float oz = (t00.z * a + t10.z * ia) * b + (t01.z * a + t11.z * ia) * ib;

    out[i * 3 + 0] = ox;
    out[i * 3 + 1] = oy;
    out[i * 3 + 2] = oz;
}

// ===========================================================================
// Fallback (byte-identical logic to the R1-passing kernel): 12 scalar
// dword gathers straight from the RGB texture. Used if d_ws is too small.
// ===========================================================================
__global__ __launch_bounds__(256) void dtx_scalar(
    const float* __restrict__ uvs,
    const float* __restrict__ tex,
    float* __restrict__ out,
    int n)
{
    int i = blockIdx.x * blockDim.x + threadIdx.x;
    if (i >= n) return;

    float2 uv = reinterpret_cast<const float2*>(uvs)[i];

    float u = (uv.x + 1.0f) * 0.5f * (float)(TEX_W - 1);
    float v = (uv.y + 1.0f) * 0.5f * (float)(TEX_H - 1);

    float fu0 = floorf(u);
    float fv0 = floorf(v);
    int u0 = (int)fu0;
    int v0 = (int)fv0;
    int u1 = (int)ceilf(u);
    int v1 = (int)ceilf(v);

    float a = u - fu0;
    float b = v - fv0;
    float ia = 1.0f - a;
    float ib = 1.0f - b;

    const float* r0 = tex + u0 * (TEX_H * 3);
    const float* r1 = tex + u1 * (TEX_H * 3);
    int c0 = v0 * 3;
    int c1 = v1 * 3;

    float t00x = r0[c0 + 0], t00y = r0[c0 + 1], t00z = r0[c0 + 2];
    float t10x = r1[c0 + 0], t10y = r1[c0 + 1], t10z = r1[c0 + 2];
    float t01x = r0[c1 + 0], t01y = r0[c1 + 1], t01z = r0[c1 + 2];
    float t11x = r1[c1 + 0], t11y = r1[c1 + 1], t11z = r1[c1 + 2];

    float ox = (t00x * a + t10x * ia) * b + (t01x * a + t11x * ia) * ib;
    float oy = (t00y * a + t10y * ia) * b + (t01y * a + t11y * ia) * ib;
    float oz = (t00z * a + t10z * ia) * b + (t01z * a + t11z * ia) * ib;

    out[i * 3 + 0] = ox;
    out[i * 3 + 1] = oy;
    out[i * 3 + 2] = oz;
}

extern "C" void kernel_launch(void* const* d_in, const int* in_sizes, int n_in,
                              void* d_out, int out_size, void* d_ws, size_t ws_size,
                              hipStream_t stream) {
    const float* uvs = (const float*)d_in[0];   // [N,2] f32
    const float* tex = (const float*)d_in[1];   // [2048,2048,3] f32
    float* out = (float*)d_out;                 // [N,3] f32

    int n = in_sizes[0] / 2;
    int block = 256;
    int grid = (n + block - 1) / block;

    if (ws_size >= RGBA_BYTES) {
        int quads = N_TEXELS / 4;                       // 1,048,576
        int pk_grid = (quads + block - 1) / block;      // 4096
        dtx_repack<<<pk_grid, block, 0, stream>>>(
            (const float4*)tex, (float4*)d_ws, quads);
        dtx_gather<<<grid, block, 0, stream>>>(
            uvs, (const float4*)d_ws, out, n);
    } else {
        dtx_scalar<<<grid, block, 0, stream>>>(uvs, tex, out, n);
    }
}